// Round 4
// baseline (874.825 us; speedup 1.0000x reference)
//
#include <hip/hip_runtime.h>
#include <stdint.h>

// ============================================================================
// ExpertMLP: out = relu(x @ W_fc^T)^2 @ W_proj^T    (fp32 in/out, bf16 MFMA)
// R10: GEMM1 rebuilt as single-pass high-occupancy kernel (gemm_fc):
//   BM=256 BN=512 BK=32, 1024 thr / 16 waves (2Mx8N, wave 128x64),
//   grid 8x32 = 256 blocks = 1 block/CU (one pass, no pass-boundary drain),
//   LDS 3 x 48 KiB rotation (stage target = buffer read at t-1, dead by the
//   end-of-(t-1) barrier), counted lgkm(4)/lgkm(0) within tile, vmcnt(3)
//   steady-state, ONE barrier per K-tile. 4 waves/SIMD occupancy.
// GEMM2 (gemm_skew, verified ~floor) and cvt_all byte-identical to R8/R9.
// ws: h[64Mi] | x_bf[16Mi] | wfc_bf[8Mi] | wproj_bf[8Mi] = 96 MiB.
// ============================================================================

typedef __attribute__((ext_vector_type(8))) short bf16x8;   // 8 bf16 = 4 VGPRs
typedef __attribute__((ext_vector_type(4))) float f32x4;    // MFMA C/D

typedef const __attribute__((address_space(1))) unsigned int* gas_u32p;
typedef __attribute__((address_space(3))) unsigned int* las_u32p;

__device__ __forceinline__ void load16_to_lds(const void* gptr, void* lptr) {
    __builtin_amdgcn_global_load_lds((gas_u32p)gptr, (las_u32p)lptr, 16, 0, 0);
}

__device__ __forceinline__ void dsr128(bf16x8& d, unsigned off) {
    asm volatile("ds_read_b128 %0, %1" : "=v"(d) : "v"(off));
}

__device__ __forceinline__ unsigned short f2bf(float f) {
    unsigned int u = __float_as_uint(f);
    u += 0x7FFFu + ((u >> 16) & 1u);   // RNE; finite inputs
    return (unsigned short)(u >> 16);
}

#define LGKM(n) do { \
    asm volatile("s_waitcnt lgkmcnt(%0)" :: "i"(n) : "memory"); \
    __builtin_amdgcn_sched_barrier(0); } while (0)
#define VMC(n) do { \
    asm volatile("s_waitcnt vmcnt(%0)" :: "i"(n) : "memory"); \
    __builtin_amdgcn_sched_barrier(0); } while (0)

// --------------------------------------------------------------------------
// Single fused fp32->bf16 prepass: x (2M float4) | W_fc (1M) | W_proj (1M).
// --------------------------------------------------------------------------
__global__ void cvt_all(const float4* __restrict__ x,  ushort4* __restrict__ xb,
                        const float4* __restrict__ wf, ushort4* __restrict__ wfb,
                        const float4* __restrict__ wp, ushort4* __restrict__ wpb)
{
    const int base = blockIdx.x * 1024 + threadIdx.x;
    #pragma unroll
    for (int j = 0; j < 4; j++) {
        const int i = base + j * 256;
        const float4* s; ushort4* d; int k;
        if (i < (1 << 21))            { s = x;  d = xb;  k = i; }
        else if (i < 3 * (1 << 20))   { s = wf; d = wfb; k = i - (1 << 21); }
        else                          { s = wp; d = wpb; k = i - 3 * (1 << 20); }
        float4 v = s[k];
        ushort4 o;
        o.x = f2bf(v.x); o.y = f2bf(v.y); o.z = f2bf(v.z); o.w = f2bf(v.w);
        d[k] = o;
    }
}

// --------------------------------------------------------------------------
// GEMM1: C[M,N] = relu(A[M,K].B[N,K]^T)^2, bf16 out.
// BM=256 BN=512 BK=32, 1024 thr, 16 waves 2Mx8N (wave 128x64).
// LDS buffer (48 KiB): A [256][32] (16 KiB) | B [512][32] (32 KiB), x3 bufs.
// Per K-tile: issue b(4) a(8) ds_read_b128; STAGE(t+2) -> prv (3 gload_lds);
//   lgkm(4): b+a0..3 done -> c1 (16 MFMA); lgkm(0): a4..7 done -> c2 (16);
//   vmcnt(3): tile t+1 staged-data arrived (3 calls of t+2 in flight);
//   barrier; rotate {prv<-cur<-nxt<-prv}.
// Race-freedom: stage target prv == buffer read at t-1; every wave completed
// its reads of it (own lgkm(0)) before the end-of-(t-1) barrier.
// --------------------------------------------------------------------------
__global__ __launch_bounds__(1024, 1)
void gemm_fc(const unsigned short* __restrict__ A,
             const unsigned short* __restrict__ B,
             unsigned short* __restrict__ C, int M, int N, int K)
{
    constexpr int AB   = 16384;           // A region: 256r x 32k x 2B
    constexpr int BB   = 32768;           // B region: 512r x 32k x 2B
    constexpr int BUFB = AB + BB;         // 48 KiB
    (void)M;

    __shared__ char lds[3 * BUFB];        // 144 KiB

    const int tid  = threadIdx.x;
    const int lane = tid & 63;
    const int wave = tid >> 6;            // 0..15
    const int wm   = wave >> 3;           // 0..1 -> rows wm*128
    const int wn   = wave & 7;            // 0..7 -> cols wn*64
    const int quad = lane >> 4;
    const int m16  = lane & 15;

    // T1: XCD swizzle (grid 8x32 = 256 blocks, %8==0, bijective)
    const int gx = gridDim.x;             // 8
    int flat = blockIdx.y * gx + blockIdx.x;
    const int cpx = (gx * gridDim.y) >> 3;
    flat = (flat & 7) * cpx + (flat >> 3);
    const long bm0 = (long)(flat / gx) * 256;
    const long bn0 = (long)(flat % gx) * 512;

    // staging: row = tid/4 (0..255), 16B chunk pre-swizzled at source so the
    // linear gload_lds dest + XOR'd ds_read agree (both use row bits 1-2).
    const int srow   = tid >> 2;
    const int schunk = (tid & 3) ^ ((tid >> 3) & 3);
    const unsigned short* gA = A + (bm0 + srow) * (long)K + schunk * 8;
    const unsigned short* gB = B + (bn0 + srow) * (long)K + schunk * 8;

    // swizzled ds_read offsets (region-local lo = row*64 + quad*16)
    unsigned offA[8], offB[4];
    #pragma unroll
    for (int i = 0; i < 8; i++) {
        const unsigned lo = (unsigned)((wm * 128 + i * 16 + m16) * 64 + quad * 16);
        offA[i] = lo ^ (((lo >> 7) & 3) << 4);
    }
    #pragma unroll
    for (int j = 0; j < 4; j++) {
        const unsigned lo = (unsigned)((wn * 64 + j * 16 + m16) * 64 + quad * 16);
        offB[j] = AB + (lo ^ (((lo >> 7) & 3) << 4));
    }

    const unsigned base =
        (unsigned)(unsigned long long)(las_u32p)(void*)lds;

    f32x4 acc[8][4];
    #pragma unroll
    for (int i = 0; i < 8; i++)
        #pragma unroll
        for (int j = 0; j < 4; j++)
            acc[i][j] = (f32x4)0.0f;

    const int NT = K >> 5;   // BK=32

    // 3 staging calls per tile: A (1 x 16KiB), B rows 0-255, B rows 256-511.
    #define STG(po_, t_) do { \
        char* _d = (char*)lds + (po_) + tid * 16; \
        const unsigned short* _sA = gA + (long)(t_) * 32; \
        load16_to_lds(_sA, _d); \
        const unsigned short* _sB = gB + (long)(t_) * 32; \
        load16_to_lds(_sB, _d + AB); \
        load16_to_lds(_sB + 256l * K, _d + AB + 16384); } while (0)

    // prologue: stage t0 -> buf0, t1 -> buf1; vmcnt(3) retires t0's 3 calls.
    STG(0, 0);
    if (NT > 1) {
        STG(BUFB, 1);
        VMC(3);
    } else {
        VMC(0);
    }
    __builtin_amdgcn_s_barrier();

    unsigned co = 0, no = BUFB, po = 2 * BUFB;

    for (int t = 0; t < NT; ++t) {
        bf16x8 a[8], b[4];

        // issue order fixed (counted lgkm depends on it): b0..3, a0..3, a4..7
        #pragma unroll
        for (int j = 0; j < 4; j++) dsr128(b[j], base + co + offB[j]);
        #pragma unroll
        for (int i = 0; i < 8; i++) dsr128(a[i], base + co + offA[i]);

        if (t + 2 < NT) STG(po, t + 2);   // prv: read at t-1, dead by barrier

        // c1: a0..3 x b  (first 8 of 12 reads complete at <=4 outstanding)
        LGKM(4);
        __builtin_amdgcn_s_setprio(1);
        #pragma unroll
        for (int i = 0; i < 4; i++)
            #pragma unroll
            for (int j = 0; j < 4; j++)
                acc[i][j] = __builtin_amdgcn_mfma_f32_16x16x32_bf16(
                    a[i], b[j], acc[i][j], 0, 0, 0);
        __builtin_amdgcn_s_setprio(0);

        // c2: a4..7 x b  (remaining 4 reads drained under c1)
        LGKM(0);
        __builtin_amdgcn_s_setprio(1);
        #pragma unroll
        for (int i = 0; i < 4; i++)
            #pragma unroll
            for (int j = 0; j < 4; j++)
                acc[4 + i][j] = __builtin_amdgcn_mfma_f32_16x16x32_bf16(
                    a[4 + i], b[j], acc[4 + i][j], 0, 0, 0);
        __builtin_amdgcn_s_setprio(0);

        // retire tile t+1's staging (3 calls of t+2 remain in flight)
        if (t + 2 < NT) VMC(3);
        else            VMC(0);
        __builtin_amdgcn_s_barrier();

        const unsigned tmp = po; po = co; co = no; no = tmp;
    }
    #undef STG

    // epilogue: relu^2 + bf16 store; C/D layout col=lane&15, row=quad*4+reg
    const long baseRow = bm0 + wm * 128 + quad * 4;
    const long baseCol = bn0 + wn * 64 + m16;
    #pragma unroll
    for (int i = 0; i < 8; i++) {
        #pragma unroll
        for (int j = 0; j < 4; j++) {
            #pragma unroll
            for (int r = 0; r < 4; r++) {
                float v = acc[i][j][r];
                v = (v > 0.0f) ? v * v : 0.0f;
                const long row = baseRow + i * 16 + r;
                const long col = baseCol + j * 16;
                C[row * (long)N + col] = f2bf(v);
            }
        }
    }
}

// --------------------------------------------------------------------------
// GEMM2 kernel (unchanged, verified ~floor): C = A.B^T fp32 out.
// BM=256 BN=128 BK=64, 512 thr, 8 waves 4Mx2N (wave 64x64), skewed 2-phase.
// --------------------------------------------------------------------------
__global__ __launch_bounds__(512, 2)
void gemm_skew(const unsigned short* __restrict__ A,
               const unsigned short* __restrict__ B,
               float* __restrict__ C, int M, int N, int K)
{
    constexpr int AKH  = 16384;            // A kh-region: 256r x 32k x 2B
    constexpr int BKH  = 8192;             // B kh-region: 128r x 32k x 2B
    constexpr int BOFF = 2 * AKH;
    constexpr int BUFB = 2 * AKH + 2 * BKH;   // 48 KiB
    (void)M;

    __shared__ char lds[2 * BUFB];            // 96 KiB

    const int tid  = threadIdx.x;
    const int lane = tid & 63;
    const int wave = tid >> 6;
    const int wm   = wave >> 1;            // 0..3 -> rows wm*64
    const int wn   = wave & 1;             // 0..1 -> cols wn*64
    const int quad = lane >> 4;
    const int m16  = lane & 15;

    // T1: XCD swizzle (grid 8x32 = 256 blocks, %8==0)
    const int gx = gridDim.x;
    int flat = blockIdx.y * gx + blockIdx.x;
    const int cpx = (gx * gridDim.y) >> 3;
    flat = (flat & 7) * cpx + (flat >> 3);
    const long bm0 = (long)(flat / gx) * 256;
    const long bn0 = (long)(flat % gx) * 128;

    const int srow   = tid >> 2;
    const int schunk = (tid & 3) ^ ((tid >> 3) & 3);
    const unsigned short* gA = A + (bm0 + srow) * (long)K + schunk * 8;
    const unsigned short* gB = B + (bn0 + srow) * (long)K + schunk * 8;

    unsigned offA[4], offB[4];
    #pragma unroll
    for (int i = 0; i < 4; i++) {
        const unsigned lo = (unsigned)((wm * 64 + i * 16 + m16) * 64 + quad * 16);
        offA[i] = lo ^ (((lo >> 7) & 3) << 4);
    }
    #pragma unroll
    for (int j = 0; j < 4; j++) {
        const unsigned lo = (unsigned)((wn * 64 + j * 16 + m16) * 64 + quad * 16);
        offB[j] = lo ^ (((lo >> 7) & 3) << 4);
    }

    const unsigned ldsbase =
        (unsigned)(unsigned long long)(las_u32p)(void*)lds;

    f32x4 acc[4][4];
    #pragma unroll
    for (int i = 0; i < 4; i++)
        #pragma unroll
        for (int j = 0; j < 4; j++)
            acc[i][j] = (f32x4)0.0f;

    const int NT = K >> 6;

    #define STAGE2(t, kh) do { \
        char* _dA = (char*)lds + ((t) & 1) * BUFB + (kh) * AKH + tid * 16; \
        const unsigned short* _sA = gA + (long)(t) * 64 + (kh) * 32; \
        load16_to_lds(_sA, _dA); \
        load16_to_lds(_sA + 128l * K, _dA + 8192); \
        char* _dB = (char*)lds + ((t) & 1) * BUFB + BOFF + (kh) * BKH + tid * 16; \
        load16_to_lds(gB + (long)(t) * 64 + (kh) * 32, _dB); } while (0)

    STAGE2(0, 0); STAGE2(0, 1);
    if (NT > 1) {
        STAGE2(1, 0);
        asm volatile("s_waitcnt vmcnt(3)" ::: "memory");
    } else {
        asm volatile("s_waitcnt vmcnt(0)" ::: "memory");
    }
    __builtin_amdgcn_sched_barrier(0);
    __builtin_amdgcn_s_barrier();

    for (int t = 0; t < NT; ++t) {
        const unsigned bufo = ldsbase + (unsigned)((t & 1) * BUFB);
        bf16x8 a0[4], b0[4], a1[4], b1[4];

        #pragma unroll
        for (int i = 0; i < 4; i++) dsr128(a0[i], bufo + offA[i]);
        #pragma unroll
        for (int j = 0; j < 4; j++) dsr128(b0[j], bufo + BOFF + offB[j]);
        #pragma unroll
        for (int i = 0; i < 4; i++) dsr128(a1[i], bufo + AKH + offA[i]);
        #pragma unroll
        for (int j = 0; j < 4; j++) dsr128(b1[j], bufo + BOFF + BKH + offB[j]);
        if (t + 1 < NT) STAGE2(t + 1, 1);
        __builtin_amdgcn_s_barrier();
        asm volatile("s_waitcnt lgkmcnt(8)" ::: "memory");
        __builtin_amdgcn_sched_barrier(0);
        __builtin_amdgcn_s_setprio(1);
        #pragma unroll
        for (int i = 0; i < 4; i++)
            #pragma unroll
            for (int j = 0; j < 4; j++)
                acc[i][j] = __builtin_amdgcn_mfma_f32_16x16x32_bf16(
                    a0[i], b0[j], acc[i][j], 0, 0, 0);
        __builtin_amdgcn_s_setprio(0);
        __builtin_amdgcn_s_barrier();

        if (t + 2 < NT) STAGE2(t + 2, 0);
        asm volatile("s_waitcnt lgkmcnt(0)" ::: "memory");
        __builtin_amdgcn_sched_barrier(0);
        __builtin_amdgcn_s_setprio(1);
        #pragma unroll
        for (int i = 0; i < 4; i++)
            #pragma unroll
            for (int j = 0; j < 4; j++)
                acc[i][j] = __builtin_amdgcn_mfma_f32_16x16x32_bf16(
                    a1[i], b1[j], acc[i][j], 0, 0, 0);
        __builtin_amdgcn_s_setprio(0);
        if (t + 2 < NT) asm volatile("s_waitcnt vmcnt(3)" ::: "memory");
        else            asm volatile("s_waitcnt vmcnt(0)" ::: "memory");
        __builtin_amdgcn_sched_barrier(0);
        __builtin_amdgcn_s_barrier();
    }
    #undef STAGE2

    const long baseRow = bm0 + wm * 64 + quad * 4;
    const long baseCol = bn0 + wn * 64 + m16;
    #pragma unroll
    for (int i = 0; i < 4; i++) {
        #pragma unroll
        for (int j = 0; j < 4; j++) {
            #pragma unroll
            for (int r = 0; r < 4; r++) {
                const long row = baseRow + i * 16 + r;
                const long col = baseCol + j * 16;
                C[row * (long)N + col] = acc[i][j][r];
            }
        }
    }
}

extern "C" void kernel_launch(void* const* d_in, const int* in_sizes, int n_in,
                              void* d_out, int out_size, void* d_ws, size_t ws_size,
                              hipStream_t stream) {
    (void)in_sizes; (void)n_in; (void)out_size; (void)ws_size;

    const int T = 8192, DIM = 1024, HID = 4096;

    const float* x     = (const float*)d_in[0];  // [T, DIM]
    const float* W_fc  = (const float*)d_in[1];  // [HID, DIM]
    const float* W_prj = (const float*)d_in[2];  // [DIM, HID]
    float* out = (float*)d_out;                  // [T, DIM]

    char* ws = (char*)d_ws;
    unsigned short* h   = (unsigned short*)ws;                  // 64 MiB [T,HID]
    unsigned short* xb  = (unsigned short*)(ws + (64l << 20));  // 16 MiB
    unsigned short* wfb = (unsigned short*)(ws + (80l << 20));  //  8 MiB
    unsigned short* wpb = (unsigned short*)(ws + (88l << 20));  //  8 MiB

    // prepass: all three fp32 -> bf16 in ONE launch
    cvt_all<<<4096, 256, 0, stream>>>(
        (const float4*)x,     (ushort4*)xb,
        (const float4*)W_fc,  (ushort4*)wfb,
        (const float4*)W_prj, (ushort4*)wpb);

    // GEMM1: h = relu(x . W_fc^T)^2  [8192,4096] bf16, 256x512 single-pass
    gemm_fc<<<dim3(HID / 512, T / 256), dim3(1024), 0, stream>>>(
        xb, wfb, h, T, HID, DIM);

    // GEMM2: out = h . W_proj^T      [8192,1024] fp32, 256x128 skewed kernel
    gemm_skew<<<dim3(DIM / 128, T / 256), dim3(512), 0, stream>>>(
        h, wpb, out, T, DIM, HID);
}

// Round 5
// 248.611 us; speedup vs baseline: 3.5189x; 3.5189x over previous
//
#include <hip/hip_runtime.h>
#include <stdint.h>

// ============================================================================
// ExpertMLP: out = relu(x @ W_fc^T)^2 @ W_proj^T    (fp32 in/out, bf16 MFMA)
// R11: revert R10 (1024-thr kernel spilled: VGPR cap 128 @ 4 waves/SIMD).
//   GEMM1 = gemm_fc2: R8's verified gemm8p<NF=4> K-loop, made PERSISTENT:
//     grid 8x32 = 256 blocks = 1 block/CU, each block does n-tiles bx and
//     bx+8. Transition issues half-2 prologue loads BEFORE half-1 epilogue
//     so prologue HBM latency hides under the C-stores. Inner K-loop,
//     LDS layout, swizzles byte-identical to R8's verified gemm8p.
//   GEMM2 = gemm_skew (verified), cvt_all byte-identical.
// ws: h[64Mi] | x_bf[16Mi] | wfc_bf[8Mi] | wproj_bf[8Mi] = 96 MiB.
// ============================================================================

typedef __attribute__((ext_vector_type(8))) short bf16x8;   // 8 bf16 = 4 VGPRs
typedef __attribute__((ext_vector_type(4))) float f32x4;    // MFMA C/D

typedef const __attribute__((address_space(1))) unsigned int* gas_u32p;
typedef __attribute__((address_space(3))) unsigned int* las_u32p;

__device__ __forceinline__ void load16_to_lds(const void* gptr, void* lptr) {
    __builtin_amdgcn_global_load_lds((gas_u32p)gptr, (las_u32p)lptr, 16, 0, 0);
}

__device__ __forceinline__ void dsr128(bf16x8& d, unsigned off) {
    asm volatile("ds_read_b128 %0, %1" : "=v"(d) : "v"(off));
}

__device__ __forceinline__ unsigned short f2bf(float f) {
    unsigned int u = __float_as_uint(f);
    u += 0x7FFFu + ((u >> 16) & 1u);   // RNE; finite inputs
    return (unsigned short)(u >> 16);
}

#define LGKM0_FENCE() do { \
    asm volatile("s_waitcnt lgkmcnt(0)" ::: "memory"); \
    __builtin_amdgcn_sched_barrier(0); } while (0)
#define VMC(n) do { \
    asm volatile("s_waitcnt vmcnt(%0)" :: "i"(n) : "memory"); \
    __builtin_amdgcn_sched_barrier(0); } while (0)

// --------------------------------------------------------------------------
// Single fused fp32->bf16 prepass: x (2M float4) | W_fc (1M) | W_proj (1M).
// (branches are block-uniform: region boundaries align to block extents)
// --------------------------------------------------------------------------
__global__ void cvt_all(const float4* __restrict__ x,  ushort4* __restrict__ xb,
                        const float4* __restrict__ wf, ushort4* __restrict__ wfb,
                        const float4* __restrict__ wp, ushort4* __restrict__ wpb)
{
    const int base = blockIdx.x * 1024 + threadIdx.x;
    #pragma unroll
    for (int j = 0; j < 4; j++) {
        const int i = base + j * 256;
        const float4* s; ushort4* d; int k;
        if (i < (1 << 21))            { s = x;  d = xb;  k = i; }
        else if (i < 3 * (1 << 20))   { s = wf; d = wfb; k = i - (1 << 21); }
        else                          { s = wp; d = wpb; k = i - 3 * (1 << 20); }
        float4 v = s[k];
        ushort4 o;
        o.x = f2bf(v.x); o.y = f2bf(v.y); o.z = f2bf(v.z); o.w = f2bf(v.w);
        d[k] = o;
    }
}

// --------------------------------------------------------------------------
// GEMM1: h = relu(A.B^T)^2, bf16 out. BM=BN=256 BK=64, 512 thr, 8 waves
// (2Mx4N, wave 128x64). R8-verified 4-phase K-loop; persistent over two
// n-tiles (bx, bx+8). LDS 2 x 64 KiB double buffer.
// K-tile ledger (entry: 6 loads of tile t+1 in flight):
//  p1 reads B.kh0+A.mh0.kh0, stages (t+1).kh1-A (+2=8)
//  p2 reads A.mh1.kh0,       stages (t+2).kh0-B (+2=10)
//  p3 reads B.kh1+A.mh0.kh1, stages (t+2).kh0-A (+2=12)
//  p4 reads A.mh1.kh1,       stages (t+2).kh1-B (+2=14); vmcnt(6) retires t+1.
// --------------------------------------------------------------------------
__global__ __launch_bounds__(512, 2)
void gemm_fc2(const unsigned short* __restrict__ A,
              const unsigned short* __restrict__ B,
              unsigned short* __restrict__ C, int M, int N, int K)
{
    constexpr int AKH  = 16384;             // A kh-region: 256r x 32k x 2B
    constexpr int BKH  = 16384;             // B kh-region: 256r x 32k x 2B
    constexpr int BOFF = 2 * AKH;
    constexpr int BUFB = 2 * AKH + 2 * BKH; // 64 KiB
    constexpr int KEEP = 6;
    (void)M;

    __shared__ char lds[2 * BUFB];          // 128 KiB

    const int tid  = threadIdx.x;
    const int lane = tid & 63;
    const int wave = tid >> 6;
    const int wm   = wave >> 2;             // 0..1 -> rows wm*128
    const int wn   = wave & 3;              // 0..3 -> cols wn*64
    const int quad = lane >> 4;
    const int m16  = lane & 15;

    // T1: XCD swizzle (grid 8x32 = 256 blocks). Each XCD gets n-cols
    // {xcd, xcd+8} across all m-rows — same panel assignment as R8.
    const int gx = gridDim.x;               // 8
    int flat = blockIdx.y * gx + blockIdx.x;
    const int cpx = (gx * gridDim.y) >> 3;  // 32
    flat = (flat & 7) * cpx + (flat >> 3);
    const long bm0    = (long)(flat / gx) * 256;
    const int  bnbase = flat % gx;          // 0..7; halves at bnbase, bnbase+8

    // staging: row = tid/4 (+128 on call 2), chunk pre-swizzled at source
    const int srow   = tid >> 2;
    const int schunk = (tid & 3) ^ ((tid >> 3) & 3);
    const unsigned short* gA  = A + (bm0 + srow) * (long)K + schunk * 8;
    const unsigned short* gB0 = B + ((long)bnbase * 256 + srow) * (long)K + schunk * 8;
    const unsigned short* gB1 = gB0 + (long)8 * 256 * K;

    // swizzled per-kh-region ds_read offsets (lo = row*64 + quad*16)
    unsigned offA[8], offB[4];
    #pragma unroll
    for (int i = 0; i < 8; i++) {
        const unsigned lo = (unsigned)((wm * 128 + i * 16 + m16) * 64 + quad * 16);
        offA[i] = lo ^ (((lo >> 7) & 3) << 4);
    }
    #pragma unroll
    for (int j = 0; j < 4; j++) {
        const unsigned lo = (unsigned)((wn * 64 + j * 16 + m16) * 64 + quad * 16);
        offB[j] = lo ^ (((lo >> 7) & 3) << 4);
    }

    char* lbase = (char*)lds;

    f32x4 acc[8][4];
    #pragma unroll
    for (int i = 0; i < 8; i++)
        #pragma unroll
        for (int j = 0; j < 4; j++)
            acc[i][j] = (f32x4)0.0f;

    const int NT = K >> 6;   // 16

    #define STG_A(t, kh) do { \
        char* _d = lbase + ((t) & 1) * BUFB + (kh) * AKH + tid * 16; \
        const unsigned short* _s = gA + (long)(t) * 64 + (kh) * 32; \
        load16_to_lds(_s, _d); \
        load16_to_lds(_s + 128l * K, _d + 8192); } while (0)

    #define STG_B(g, t, kh) do { \
        char* _d = lbase + ((t) & 1) * BUFB + BOFF + (kh) * BKH + tid * 16; \
        const unsigned short* _s = (g) + (long)(t) * 64 + (kh) * 32; \
        load16_to_lds(_s, _d); \
        load16_to_lds(_s + 128l * K, _d + 8192); } while (0)

    // 14 loads: t0 fully (8) + t1 {B.kh0, A.kh0, B.kh1} (6)
    #define PROLOGUE(g) do { \
        STG_B(g, 0, 0); STG_A(0, 0); STG_B(g, 0, 1); STG_A(0, 1); \
        STG_B(g, 1, 0); STG_A(1, 0); STG_B(g, 1, 1); } while (0)

    // R8-verified 4-phase K-loop (NF=4), stages from B-pointer g.
    #define KLOOP(g) \
    for (int t = 0; t < NT; ++t) { \
        char* bufA = lbase + (t & 1) * BUFB; \
        char* bufB = bufA + BOFF; \
        bf16x8 af[4], bf[4]; \
        _Pragma("unroll") \
        for (int j = 0; j < 4; j++) bf[j] = *(const bf16x8*)(bufB + offB[j]); \
        _Pragma("unroll") \
        for (int i = 0; i < 4; i++) af[i] = *(const bf16x8*)(bufA + offA[i]); \
        if (t + 1 < NT) STG_A(t + 1, 1); \
        __builtin_amdgcn_s_barrier(); \
        LGKM0_FENCE(); \
        __builtin_amdgcn_s_setprio(1); \
        _Pragma("unroll") \
        for (int i = 0; i < 4; i++) \
            _Pragma("unroll") \
            for (int j = 0; j < 4; j++) \
                acc[i][j] = __builtin_amdgcn_mfma_f32_16x16x32_bf16( \
                    af[i], bf[j], acc[i][j], 0, 0, 0); \
        __builtin_amdgcn_s_setprio(0); \
        __builtin_amdgcn_s_barrier(); \
        _Pragma("unroll") \
        for (int i = 0; i < 4; i++) af[i] = *(const bf16x8*)(bufA + offA[4 + i]); \
        if (t + 2 < NT) STG_B(g, t + 2, 0); \
        __builtin_amdgcn_s_barrier(); \
        LGKM0_FENCE(); \
        __builtin_amdgcn_s_setprio(1); \
        _Pragma("unroll") \
        for (int i = 0; i < 4; i++) \
            _Pragma("unroll") \
            for (int j = 0; j < 4; j++) \
                acc[4 + i][j] = __builtin_amdgcn_mfma_f32_16x16x32_bf16( \
                    af[i], bf[j], acc[4 + i][j], 0, 0, 0); \
        __builtin_amdgcn_s_setprio(0); \
        __builtin_amdgcn_s_barrier(); \
        _Pragma("unroll") \
        for (int j = 0; j < 4; j++) bf[j] = *(const bf16x8*)(bufB + BKH + offB[j]); \
        _Pragma("unroll") \
        for (int i = 0; i < 4; i++) af[i] = *(const bf16x8*)(bufA + AKH + offA[i]); \
        if (t + 2 < NT) STG_A(t + 2, 0); \
        __builtin_amdgcn_s_barrier(); \
        LGKM0_FENCE(); \
        __builtin_amdgcn_s_setprio(1); \
        _Pragma("unroll") \
        for (int i = 0; i < 4; i++) \
            _Pragma("unroll") \
            for (int j = 0; j < 4; j++) \
                acc[i][j] = __builtin_amdgcn_mfma_f32_16x16x32_bf16( \
                    af[i], bf[j], acc[i][j], 0, 0, 0); \
        __builtin_amdgcn_s_setprio(0); \
        __builtin_amdgcn_s_barrier(); \
        _Pragma("unroll") \
        for (int i = 0; i < 4; i++) af[i] = *(const bf16x8*)(bufA + AKH + offA[4 + i]); \
        if (t + 2 < NT) STG_B(g, t + 2, 1); \
        __builtin_amdgcn_s_barrier(); \
        LGKM0_FENCE(); \
        __builtin_amdgcn_s_setprio(1); \
        _Pragma("unroll") \
        for (int i = 0; i < 4; i++) \
            _Pragma("unroll") \
            for (int j = 0; j < 4; j++) \
                acc[4 + i][j] = __builtin_amdgcn_mfma_f32_16x16x32_bf16( \
                    af[i], bf[j], acc[4 + i][j], 0, 0, 0); \
        __builtin_amdgcn_s_setprio(0); \
        if (t + 2 < NT) VMC(KEEP); \
        else            VMC(0); \
        __builtin_amdgcn_s_barrier(); \
    }

    // epilogue: relu^2 + bf16 store + acc re-zero.
    #define EPILOGUE(half) do { \
        const long bn0 = (long)(bnbase + (half) * 8) * 256; \
        const long baseRow = bm0 + wm * 128 + quad * 4; \
        const long baseCol = bn0 + wn * 64 + m16; \
        _Pragma("unroll") \
        for (int i = 0; i < 8; i++) { \
            _Pragma("unroll") \
            for (int j = 0; j < 4; j++) { \
                _Pragma("unroll") \
                for (int r = 0; r < 4; r++) { \
                    float v = acc[i][j][r]; \
                    v = (v > 0.0f) ? v * v : 0.0f; \
                    C[(baseRow + i * 16 + r) * (long)N + baseCol + j * 16] = f2bf(v); \
                } \
                acc[i][j] = (f32x4)0.0f; \
            } \
        } } while (0)

    // ---- half 0 ----
    PROLOGUE(gB0);
    VMC(KEEP);
    __builtin_amdgcn_s_barrier();
    KLOOP(gB0);                // exits with vm=0, lgkm=0, all waves synced

    // ---- transition: issue half-1 prologue, hide it under the epilogue ----
    PROLOGUE(gB1);
    EPILOGUE(0);
    VMC(0);                    // loads completed during epilogue (cheap)
    __builtin_amdgcn_s_barrier();
    KLOOP(gB1);
    EPILOGUE(1);

    #undef STG_A
    #undef STG_B
    #undef PROLOGUE
    #undef KLOOP
    #undef EPILOGUE
}

// --------------------------------------------------------------------------
// GEMM2 kernel (unchanged, verified): C = A.B^T fp32 out.
// BM=256 BN=128 BK=64, 512 thr, 8 waves 4Mx2N (wave 64x64), skewed 2-phase.
// --------------------------------------------------------------------------
__global__ __launch_bounds__(512, 2)
void gemm_skew(const unsigned short* __restrict__ A,
               const unsigned short* __restrict__ B,
               float* __restrict__ C, int M, int N, int K)
{
    constexpr int AKH  = 16384;            // A kh-region: 256r x 32k x 2B
    constexpr int BKH  = 8192;             // B kh-region: 128r x 32k x 2B
    constexpr int BOFF = 2 * AKH;
    constexpr int BUFB = 2 * AKH + 2 * BKH;   // 48 KiB
    (void)M;

    __shared__ char lds[2 * BUFB];            // 96 KiB

    const int tid  = threadIdx.x;
    const int lane = tid & 63;
    const int wave = tid >> 6;
    const int wm   = wave >> 1;            // 0..3 -> rows wm*64
    const int wn   = wave & 1;             // 0..1 -> cols wn*64
    const int quad = lane >> 4;
    const int m16  = lane & 15;

    // T1: XCD swizzle (grid 8x32 = 256 blocks, %8==0)
    const int gx = gridDim.x;
    int flat = blockIdx.y * gx + blockIdx.x;
    const int cpx = (gx * gridDim.y) >> 3;
    flat = (flat & 7) * cpx + (flat >> 3);
    const long bm0 = (long)(flat / gx) * 256;
    const long bn0 = (long)(flat % gx) * 128;

    const int srow   = tid >> 2;
    const int schunk = (tid & 3) ^ ((tid >> 3) & 3);
    const unsigned short* gA = A + (bm0 + srow) * (long)K + schunk * 8;
    const unsigned short* gB = B + (bn0 + srow) * (long)K + schunk * 8;

    unsigned offA[4], offB[4];
    #pragma unroll
    for (int i = 0; i < 4; i++) {
        const unsigned lo = (unsigned)((wm * 64 + i * 16 + m16) * 64 + quad * 16);
        offA[i] = lo ^ (((lo >> 7) & 3) << 4);
    }
    #pragma unroll
    for (int j = 0; j < 4; j++) {
        const unsigned lo = (unsigned)((wn * 64 + j * 16 + m16) * 64 + quad * 16);
        offB[j] = lo ^ (((lo >> 7) & 3) << 4);
    }

    const unsigned ldsbase =
        (unsigned)(unsigned long long)(las_u32p)(void*)lds;

    f32x4 acc[4][4];
    #pragma unroll
    for (int i = 0; i < 4; i++)
        #pragma unroll
        for (int j = 0; j < 4; j++)
            acc[i][j] = (f32x4)0.0f;

    const int NT = K >> 6;

    #define STAGE2(t, kh) do { \
        char* _dA = (char*)lds + ((t) & 1) * BUFB + (kh) * AKH + tid * 16; \
        const unsigned short* _sA = gA + (long)(t) * 64 + (kh) * 32; \
        load16_to_lds(_sA, _dA); \
        load16_to_lds(_sA + 128l * K, _dA + 8192); \
        char* _dB = (char*)lds + ((t) & 1) * BUFB + BOFF + (kh) * BKH + tid * 16; \
        load16_to_lds(gB + (long)(t) * 64 + (kh) * 32, _dB); } while (0)

    STAGE2(0, 0); STAGE2(0, 1);
    if (NT > 1) {
        STAGE2(1, 0);
        asm volatile("s_waitcnt vmcnt(3)" ::: "memory");
    } else {
        asm volatile("s_waitcnt vmcnt(0)" ::: "memory");
    }
    __builtin_amdgcn_sched_barrier(0);
    __builtin_amdgcn_s_barrier();

    for (int t = 0; t < NT; ++t) {
        const unsigned bufo = ldsbase + (unsigned)((t & 1) * BUFB);
        bf16x8 a0[4], b0[4], a1[4], b1[4];

        #pragma unroll
        for (int i = 0; i < 4; i++) dsr128(a0[i], bufo + offA[i]);
        #pragma unroll
        for (int j = 0; j < 4; j++) dsr128(b0[j], bufo + BOFF + offB[j]);
        #pragma unroll
        for (int i = 0; i < 4; i++) dsr128(a1[i], bufo + AKH + offA[i]);
        #pragma unroll
        for (int j = 0; j < 4; j++) dsr128(b1[j], bufo + BOFF + BKH + offB[j]);
        if (t + 1 < NT) STAGE2(t + 1, 1);
        __builtin_amdgcn_s_barrier();
        asm volatile("s_waitcnt lgkmcnt(8)" ::: "memory");
        __builtin_amdgcn_sched_barrier(0);
        __builtin_amdgcn_s_setprio(1);
        #pragma unroll
        for (int i = 0; i < 4; i++)
            #pragma unroll
            for (int j = 0; j < 4; j++)
                acc[i][j] = __builtin_amdgcn_mfma_f32_16x16x32_bf16(
                    a0[i], b0[j], acc[i][j], 0, 0, 0);
        __builtin_amdgcn_s_setprio(0);
        __builtin_amdgcn_s_barrier();

        if (t + 2 < NT) STAGE2(t + 2, 0);
        asm volatile("s_waitcnt lgkmcnt(0)" ::: "memory");
        __builtin_amdgcn_sched_barrier(0);
        __builtin_amdgcn_s_setprio(1);
        #pragma unroll
        for (int i = 0; i < 4; i++)
            #pragma unroll
            for (int j = 0; j < 4; j++)
                acc[i][j] = __builtin_amdgcn_mfma_f32_16x16x32_bf16(
                    a1[i], b1[j], acc[i][j], 0, 0, 0);
        __builtin_amdgcn_s_setprio(0);
        if (t + 2 < NT) asm volatile("s_waitcnt vmcnt(3)" ::: "memory");
        else            asm volatile("s_waitcnt vmcnt(0)" ::: "memory");
        __builtin_amdgcn_sched_barrier(0);
        __builtin_amdgcn_s_barrier();
    }
    #undef STAGE2

    const long baseRow = bm0 + wm * 64 + quad * 4;
    const long baseCol = bn0 + wn * 64 + m16;
    #pragma unroll
    for (int i = 0; i < 4; i++) {
        #pragma unroll
        for (int j = 0; j < 4; j++) {
            #pragma unroll
            for (int r = 0; r < 4; r++) {
                const long row = baseRow + i * 16 + r;
                const long col = baseCol + j * 16;
                C[row * (long)N + col] = acc[i][j][r];
            }
        }
    }
}

extern "C" void kernel_launch(void* const* d_in, const int* in_sizes, int n_in,
                              void* d_out, int out_size, void* d_ws, size_t ws_size,
                              hipStream_t stream) {
    (void)in_sizes; (void)n_in; (void)out_size; (void)ws_size;

    const int T = 8192, DIM = 1024, HID = 4096;

    const float* x     = (const float*)d_in[0];  // [T, DIM]
    const float* W_fc  = (const float*)d_in[1];  // [HID, DIM]
    const float* W_prj = (const float*)d_in[2];  // [DIM, HID]
    float* out = (float*)d_out;                  // [T, DIM]

    char* ws = (char*)d_ws;
    unsigned short* h   = (unsigned short*)ws;                  // 64 MiB [T,HID]
    unsigned short* xb  = (unsigned short*)(ws + (64l << 20));  // 16 MiB
    unsigned short* wfb = (unsigned short*)(ws + (80l << 20));  //  8 MiB
    unsigned short* wpb = (unsigned short*)(ws + (88l << 20));  //  8 MiB

    // prepass: all three fp32 -> bf16 in ONE launch
    cvt_all<<<4096, 256, 0, stream>>>(
        (const float4*)x,     (ushort4*)xb,
        (const float4*)W_fc,  (ushort4*)wfb,
        (const float4*)W_prj, (ushort4*)wpb);

    // GEMM1: h = relu(x . W_fc^T)^2  [8192,4096] bf16, persistent 2-tile
    gemm_fc2<<<dim3(8, T / 256), dim3(512), 0, stream>>>(
        xb, wfb, h, T, HID, DIM);

    // GEMM2: out = h . W_proj^T      [8192,1024] fp32, 256x128 skewed kernel
    gemm_skew<<<dim3(DIM / 128, T / 256), dim3(512), 0, stream>>>(
        h, wpb, out, T, DIM, HID);
}